// Round 7
// baseline (67.814 us; speedup 1.0000x reference)
//
#include <hip/hip_runtime.h>
#include <cstdint>

#define NQ 20
#define DIM (1u << NQ)

typedef float f32x2 __attribute__((ext_vector_type(2)));
typedef float f32x4 __attribute__((ext_vector_type(4)));

// ================= constexpr GF(2) machinery =================
// Gray map g(x)=x^(x>>1) accumulates per CNOT-chain layer. Gate (l,b) is a
// butterfly with mask m=g^l(e_b) (span [b-l,b]) and selector parity(j&R),
// R = row b of g^{-l}. Commutation rule (verified): G1,G2 commute iff
// parity(m1&R2) == parity(m2&R1). Final gather: out[ginv4(j)] = buf[j].
constexpr unsigned cpair_mask(int l, int b) {
    unsigned m = 1u << b;
    for (int k = 0; k < l; ++k) m ^= m >> 1;
    return m;
}
constexpr unsigned cginv1(unsigned x) {
    x ^= x >> 1; x ^= x >> 2; x ^= x >> 4; x ^= x >> 8; x ^= x >> 16;
    return x & 0xFFFFFu;
}
constexpr unsigned csel_mask(int l, int b) {
    unsigned R = 0;
    for (int k = 0; k < NQ; ++k) {
        unsigned w = 1u << k;
        for (int t = 0; t < l; ++t) w = cginv1(w);
        if ((w >> b) & 1u) R |= 1u << k;
    }
    return R;
}
constexpr int cpopc(unsigned x) { int c = 0; while (x) { c += x & 1; x >>= 1; } return c; }
constexpr unsigned cswz(unsigned t) { return t ^ ((t >> 5) & 0xFu); }

struct GateC { unsigned R; unsigned sb; int valid; int tix; int thix; };
struct GroupC { int pv[3]; unsigned gxs[8]; unsigned lgxs[8]; GateC gt[3]; };
struct SchedC { GroupC g[12]; int ng; };
struct PhC { SchedC s; int FL, GAP; };

// local tile bits: [0,FL) global-direct, [FL,12) map to global [FL+GAP, GAP+12)
constexpr unsigned to_local(unsigned m, int FL, int GAP) {
    return (m & ((1u << FL) - 1u)) | ((m >> (FL + GAP)) << FL);
}

constexpr void addg(SchedC& s, int FL, int GAP,
                    int l0, int b0, int l1, int b1, int l2, int b2) {
    GroupC g{};
    int ls[3] = {l0, l1, l2}; int bs[3] = {b0, b1, b2};
    unsigned m[3] = {0, 0, 0};
    for (int j = 0; j < 3; ++j) {
        bool val = ls[j] >= 0;
        m[j] = val ? cpair_mask(ls[j], bs[j]) : (1u << bs[j]);   // pad: plain bit
        g.gt[j].R = val ? csel_mask(ls[j], bs[j]) : 0u;
        g.gt[j].valid = val ? 1 : 0;
        g.gt[j].tix = val ? (ls[j] * NQ + bs[j]) : 0;
        g.gt[j].thix = val ? (ls[j] * NQ + (NQ - 1 - bs[j])) : 0;
    }
    for (int e = 0; e < 8; ++e) {
        unsigned x = 0;
        for (int j = 0; j < 3; ++j) if ((e >> j) & 1) x ^= m[j];
        g.gxs[e] = x;
        g.lgxs[e] = to_local(x, FL, GAP);
    }
    for (int j = 0; j < 3; ++j) {
        unsigned sb = 0;
        for (int e = 0; e < 8; ++e) if (cpopc(g.gxs[e] & g.gt[j].R) & 1) sb |= (1u << e);
        g.gt[j].sb = sb;
    }
    int pv[3] = {0, 0, 0};
    for (int j = 0; j < 3; ++j) {
        unsigned lm = to_local(m[j], FL, GAP);
        int p = 0; for (int k = 0; k < 12; ++k) if ((lm >> k) & 1) p = k;
        pv[j] = p;
    }
    for (int a = 0; a < 2; ++a)
        for (int c = 0; c < 2 - a; ++c)
            if (pv[c] > pv[c + 1]) { int t = pv[c]; pv[c] = pv[c + 1]; pv[c + 1] = t; }
    g.pv[0] = pv[0]; g.pv[1] = pv[1]; g.pv[2] = pv[2];
    s.g[s.ng] = g; s.ng++;
}

// 3-phase schedule (commutation-verified):
//  P1 [0,11]:      l0 b0..11
//  P2 {0}u[9,19]:  l0 b12-19, l1 b10-19, l2 b11-19, l3 b12-19
//  P3 [0,11]:      l1 b0-9, l2 b0-10, l3 b3-11, l3 b0-2 (fused -> out gather)
// Cross-phase legality: low-layer-late gates commute past high-layer-early
// ones: e.g. G(1,b<=9) vs G(2,b'>=11): m1 in [0,9] misses R2={k>=b',k=b' mod2}
// -> 0; m2={b',b'-2} both >= 9 >= b inside R1={k>=b} -> parity 0. Same for
// (1,*)x(3,*), (2,*)x(3,*). Group 0 fuses into stage-in, last into stage-out.
constexpr PhC mk_phase(int ph) {
    PhC P{};
    if (ph == 0) {
        P.FL = 12; P.GAP = 8;
        addg(P.s, 12, 8, 0,0, 0,1, 0,2);            // stage-in fused
        addg(P.s, 12, 8, 0,3, 0,4, 0,5);
        addg(P.s, 12, 8, 0,6, 0,7, 0,8);
        addg(P.s, 12, 8, 0,9, 0,10, 0,11);          // stage-out fused
    } else if (ph == 1) {
        P.FL = 1; P.GAP = 8;                        // window {0} u [9,19]
        addg(P.s, 1, 8, 0,12, 0,13, 0,14);          // stage-in fused
        addg(P.s, 1, 8, 0,15, 0,16, 0,17);
        addg(P.s, 1, 8, 0,18, 0,19, 1,10);
        addg(P.s, 1, 8, 1,11, 1,12, 1,13);
        addg(P.s, 1, 8, 1,14, 1,15, 1,16);
        addg(P.s, 1, 8, 1,17, 1,18, 1,19);
        addg(P.s, 1, 8, 2,11, 2,12, 2,13);
        addg(P.s, 1, 8, 2,14, 2,15, 2,16);
        addg(P.s, 1, 8, 2,17, 2,18, 2,19);
        addg(P.s, 1, 8, 3,12, 3,13, 3,14);
        addg(P.s, 1, 8, 3,15, 3,16, 3,17);
        addg(P.s, 1, 8, 3,18, 3,19, -1,0);          // stage-out fused (1 pad)
    } else {
        P.FL = 12; P.GAP = 8;
        addg(P.s, 12, 8, 1,0, 1,1, 1,2);            // stage-in fused
        addg(P.s, 12, 8, 1,3, 1,4, 1,5);
        addg(P.s, 12, 8, 1,6, 1,7, 1,8);
        addg(P.s, 12, 8, 1,9, 2,0, 2,1);
        addg(P.s, 12, 8, 2,2, 2,3, 2,4);
        addg(P.s, 12, 8, 2,5, 2,6, 2,7);
        addg(P.s, 12, 8, 2,8, 2,9, 2,10);
        addg(P.s, 12, 8, 3,3, 3,4, 3,5);
        addg(P.s, 12, 8, 3,6, 3,7, 3,8);
        addg(P.s, 12, 8, 3,9, 3,10, 3,11);
        addg(P.s, 12, 8, 3,0, 3,1, 3,2);            // stage-out fused -> out scatter
    }
    return P;
}

__device__ __forceinline__ unsigned swz(unsigned t) { return t ^ ((t >> 5) & 0xFu); }
__device__ __forceinline__ f32x2 splat2(float x) { f32x2 r = {x, x}; return r; }

template<int FL, int GAP>
__device__ __forceinline__ unsigned gmapF(unsigned t, unsigned mid) {
    if constexpr (FL == 12) return (mid << 12) | t;
    else return (t & ((1u << FL) - 1u)) | ((mid & ((1u << GAP) - 1u)) << FL)
              | ((t >> FL) << (FL + GAP)) | ((mid >> GAP) << (GAP + 12));
}

__device__ __forceinline__ unsigned expand3(unsigned u, int p0, int p1, int p2) {
    u = ((u >> p0) << (p0 + 1)) | (u & ((1u << p0) - 1u));
    u = ((u >> p1) << (p1 + 1)) | (u & ((1u << p1) - 1u));
    u = ((u >> p2) << (p2 + 1)) | (u & ((1u << p2) - 1u));
    return u;
}

__constant__ __device__ int BASE_TBL[3][4] = {{0, 2, 4, 6}, {0, 1, 4, 5}, {0, 1, 2, 3}};

// 3 butterflies on an 8-amp register coset. G must constant-fold.
#define APPLY_GROUP(G, v, g0, cd, sd)                                           \
    {                                                                            \
        _Pragma("unroll")                                                        \
        for (int j = 0; j < 3; ++j) {                                            \
            if ((G).gt[j].valid) {                                               \
                const f32x2 cc_ = splat2((cd)[j]);                               \
                const unsigned par_ = (unsigned)__popc((g0) & (G).gt[j].R) & 1u; \
                const float sp_ = par_ ? (sd)[j] : -(sd)[j];                     \
                _Pragma("unroll")                                                \
                for (int pr = 0; pr < 4; ++pr) {                                 \
                    const int ea = BASE_TBL[j][pr];                              \
                    const int eb = ea | (1 << j);                                \
                    const f32x2 sg_ = splat2((((G).gt[j].sb >> ea) & 1u) ? -sp_ : sp_); \
                    const f32x2 a_ = v[ea], b_ = v[eb];                          \
                    v[ea] = cc_ * a_ + sg_ * b_;                                 \
                    v[eb] = cc_ * b_ - sg_ * a_;                                 \
                }                                                                \
            }                                                                    \
        }                                                                        \
    }

// ================= phase kernel =================
// 4096-amp LDS tile; 512 threads x 8-amp cosets; first/last group fused
// into global stage-in/stage-out.
template<int PH, bool IS_INIT, bool IS_FINAL>
__global__ __launch_bounds__(512) void k_phase(f32x2* __restrict__ st,
                                               const float* __restrict__ qr,
                                               const float* __restrict__ qi,
                                               const float* __restrict__ theta,
                                               float* __restrict__ out) {
    constexpr PhC P = mk_phase(PH);
    constexpr int FL = P.FL, GAP = P.GAP, NG = P.s.ng;
    __shared__ __align__(16) f32x2 lds[4096];
    __shared__ float2 trigS[80];
    const unsigned tid = threadIdx.x;
    const unsigned mid = blockIdx.x;

    if (tid < 80) {
        int l = tid / NQ, b = tid % NQ;
        float th = 0.5f * theta[l * NQ + (NQ - 1 - b)];
        trigS[tid] = make_float2(cosf(th), sinf(th));
    }

    // ---- stage-in, fused group 0 ----
    {
        constexpr GroupC G = P.s.g[0];
        const unsigned t0 = expand3(tid, G.pv[0], G.pv[1], G.pv[2]);
        const unsigned g0 = gmapF<FL, GAP>(t0, mid);
        f32x2 v[8];
        if constexpr (IS_INIT) {
            // group 0 spans bits {0,1,2} -> 8 contiguous amps; planar input
            const f32x4* r4 = reinterpret_cast<const f32x4*>(qr);
            const f32x4* i4 = reinterpret_cast<const f32x4*>(qi);
            f32x4 ra = r4[g0 >> 2], rb = r4[(g0 >> 2) + 1];
            f32x4 ia = i4[g0 >> 2], ib = i4[(g0 >> 2) + 1];
            const float re[8] = {ra.x, ra.y, ra.z, ra.w, rb.x, rb.y, rb.z, rb.w};
            const float im[8] = {ia.x, ia.y, ia.z, ia.w, ib.x, ib.y, ib.z, ib.w};
#pragma unroll
            for (int e = 0; e < 8; ++e) v[e] = f32x2{re[G.gxs[e]], im[G.gxs[e]]};
        } else {
#pragma unroll
            for (int e = 0; e < 8; ++e) v[e] = st[g0 ^ G.gxs[e]];
        }
        float cd[3], sd[3];
#pragma unroll
        for (int j = 0; j < 3; ++j)
            if (G.gt[j].valid) {
                float th = 0.5f * theta[G.gt[j].thix];
                cd[j] = cosf(th); sd[j] = sinf(th);
            }
        APPLY_GROUP(G, v, g0, cd, sd);
#pragma unroll
        for (int e = 0; e < 8; ++e) lds[swz(t0 ^ G.lgxs[e])] = v[e];
    }
    __syncthreads();

    // ---- in-LDS rounds: groups 1 .. NG-2 ----
#pragma unroll
    for (int gi = 1; gi < NG - 1; ++gi) {
        const unsigned t0 = expand3(tid, P.s.g[gi].pv[0], P.s.g[gi].pv[1], P.s.g[gi].pv[2]);
        const unsigned g0 = gmapF<FL, GAP>(t0, mid);
        const unsigned sz0 = swz(t0);
        f32x2 v[8]; unsigned ad[8];
#pragma unroll
        for (int e = 0; e < 8; ++e) {
            ad[e] = sz0 ^ cswz(P.s.g[gi].lgxs[e]);   // folds to immediate XOR
            v[e] = lds[ad[e]];
        }
        float cd[3], sd[3];
#pragma unroll
        for (int j = 0; j < 3; ++j)
            if (P.s.g[gi].gt[j].valid) {
                float2 cs = trigS[P.s.g[gi].gt[j].tix];
                cd[j] = cs.x; sd[j] = cs.y;
            }
        APPLY_GROUP(P.s.g[gi], v, g0, cd, sd);
#pragma unroll
        for (int e = 0; e < 8; ++e) lds[ad[e]] = v[e];
        __syncthreads();
    }

    // ---- stage-out, fused group NG-1 ----
    {
        constexpr GroupC G = P.s.g[NG - 1];
        const unsigned t0 = expand3(tid, G.pv[0], G.pv[1], G.pv[2]);
        const unsigned g0 = gmapF<FL, GAP>(t0, mid);
        f32x2 v[8];
#pragma unroll
        for (int e = 0; e < 8; ++e) v[e] = lds[swz(t0 ^ G.lgxs[e])];
        float cd[3], sd[3];
#pragma unroll
        for (int j = 0; j < 3; ++j)
            if (G.gt[j].valid) {
                float2 cs = trigS[G.gt[j].tix];
                cd[j] = cs.x; sd[j] = cs.y;
            }
        APPLY_GROUP(G, v, g0, cd, sd);
        if constexpr (IS_FINAL) {
            // inverse-Gray gather + planar split; group spans bits {0,1,2},
            // ginv4 is identity below bit 4 -> i(e) = ginv4(g0) ^ gxs[e].
            const unsigned i0 = g0 ^ (g0 >> 4) ^ (g0 >> 8) ^ (g0 >> 12) ^ (g0 >> 16);
#pragma unroll
            for (int e = 0; e < 8; ++e) {
                const unsigned i = i0 ^ G.gxs[e];
                out[i] = v[e].x;
                out[DIM + i] = v[e].y;
            }
        } else {
#pragma unroll
            for (int e = 0; e < 8; ++e) st[g0 ^ G.gxs[e]] = v[e];
        }
    }
}

// ================= launch =================
extern "C" void kernel_launch(void* const* d_in, const int* in_sizes, int n_in,
                              void* d_out, int out_size, void* d_ws, size_t ws_size,
                              hipStream_t stream) {
    const float* theta = (const float*)d_in[0];   // (4,20) float32
    const float* qr    = (const float*)d_in[1];
    const float* qi    = (const float*)d_in[2];
    float* out = (float*)d_out;
    f32x2* st = (f32x2*)d_ws;                     // 8 MiB interleaved state

    k_phase<0, true,  false><<<256, 512, 0, stream>>>(st, qr, qi, theta, out);
    k_phase<1, false, false><<<256, 512, 0, stream>>>(st, qr, qi, theta, out);
    k_phase<2, false, true ><<<256, 512, 0, stream>>>(st, qr, qi, theta, out);
}

// Round 10
// 63.237 us; speedup vs baseline: 1.0724x; 1.0724x over previous
//
#include <hip/hip_runtime.h>
#include <cstdint>

#define NQ 20
#define DIM (1u << NQ)

typedef float f32x2 __attribute__((ext_vector_type(2)));
typedef float f32x4 __attribute__((ext_vector_type(4)));

// ================= constexpr GF(2) machinery =================
// Gray map g(x)=x^(x>>1) accumulates per CNOT-chain layer. Gate (l,b) is a
// butterfly with mask m=g^l(e_b) (span [b-l,b]) and selector parity(j&R),
// R = row b of g^{-l}. Commutation rule: G1,G2 commute iff
// parity(m1&R2) == parity(m2&R1). Final gather: out[ginv4(j)] = buf[j].
constexpr unsigned cpair_mask(int l, int b) {
    unsigned m = 1u << b;
    for (int k = 0; k < l; ++k) m ^= m >> 1;
    return m;
}
constexpr unsigned cginv1(unsigned x) {
    x ^= x >> 1; x ^= x >> 2; x ^= x >> 4; x ^= x >> 8; x ^= x >> 16;
    return x & 0xFFFFFu;
}
constexpr unsigned csel_mask(int l, int b) {
    unsigned R = 0;
    for (int k = 0; k < NQ; ++k) {
        unsigned w = 1u << k;
        for (int t = 0; t < l; ++t) w = cginv1(w);
        if ((w >> b) & 1u) R |= 1u << k;
    }
    return R;
}
constexpr int cpopc(unsigned x) { int c = 0; while (x) { c += x & 1; x >>= 1; } return c; }
constexpr unsigned cswz(unsigned t) { return t ^ ((t >> 5) & 0xFu); }

struct GateC { unsigned R; unsigned sb; int valid; int tix; int thix; };
struct GroupC { int pv[3]; unsigned gxs[8]; unsigned lgxs[8]; GateC gt[3]; };
struct SchedC { GroupC g[12]; int bar[12]; int ng; };
struct PhC { SchedC s; int FL, GAP, fuse_in, fuse_out; };

// local tile bits: [0,FL) global-direct, [FL,12) map to global [FL+GAP, GAP+12)
constexpr unsigned to_local(unsigned m, int FL, int GAP) {
    return (m & ((1u << FL) - 1u)) | ((m >> (FL + GAP)) << FL);
}

constexpr void addg(SchedC& s, int FL, int GAP, int bar,
                    int l0, int b0, int l1, int b1, int l2, int b2) {
    GroupC g{};
    int ls[3] = {l0, l1, l2}; int bs[3] = {b0, b1, b2};
    unsigned m[3] = {0, 0, 0};
    for (int j = 0; j < 3; ++j) {
        bool val = ls[j] >= 0;
        m[j] = val ? cpair_mask(ls[j], bs[j]) : (1u << bs[j]);   // pad: plain bit
        g.gt[j].R = val ? csel_mask(ls[j], bs[j]) : 0u;
        g.gt[j].valid = val ? 1 : 0;
        g.gt[j].tix = val ? (ls[j] * NQ + bs[j]) : 0;
        g.gt[j].thix = val ? (ls[j] * NQ + (NQ - 1 - bs[j])) : 0;
    }
    for (int e = 0; e < 8; ++e) {
        unsigned x = 0;
        for (int j = 0; j < 3; ++j) if ((e >> j) & 1) x ^= m[j];
        g.gxs[e] = x;
        g.lgxs[e] = to_local(x, FL, GAP);
    }
    for (int j = 0; j < 3; ++j) {
        unsigned sb = 0;
        for (int e = 0; e < 8; ++e) if (cpopc(g.gxs[e] & g.gt[j].R) & 1) sb |= (1u << e);
        g.gt[j].sb = sb;
    }
    int pv[3] = {0, 0, 0};
    for (int j = 0; j < 3; ++j) {
        unsigned lm = to_local(m[j], FL, GAP);
        int p = 0; for (int k = 0; k < 12; ++k) if ((lm >> k) & 1) p = k;
        pv[j] = p;
    }
    for (int a = 0; a < 2; ++a)
        for (int c = 0; c < 2 - a; ++c)
            if (pv[c] > pv[c + 1]) { int t = pv[c]; pv[c] = pv[c + 1]; pv[c + 1] = t; }
    g.pv[0] = pv[0]; g.pv[1] = pv[1]; g.pv[2] = pv[2];
    s.bar[s.ng] = bar;
    s.g[s.ng] = g; s.ng++;
}

// 4-phase schedule, SAME gate order as the verified R6 kernel.
// bar=1: __syncthreads before round (cross-wave span or guard); bar=0:
// wave-local round (union local mask span in bits [0,8]; wave id = bits
// [9,11], preserved by swizzle) -> wave_barrier only.
constexpr PhC mk_phase(int ph) {
    PhC P{};
    if (ph == 0) {
        P.FL = 12; P.GAP = 8; P.fuse_in = 1; P.fuse_out = 0;
        addg(P.s, 12, 8, 0, 0,0, 0,1, 0,2);     // fused into stage-in (contig)
        addg(P.s, 12, 8, 1, 0,3, 0,4, 0,5);     // bar: trigS guard
        addg(P.s, 12, 8, 0, 0,6, 0,7, 0,8);
        addg(P.s, 12, 8, 1, 0,9, 0,10, 0,11);   // cross-wave
    } else if (ph == 1) {
        P.FL = 4; P.GAP = 8; P.fuse_in = 0; P.fuse_out = 0;  // window [12,19]
        addg(P.s, 4, 8, 1, 0,12, 0,13, 0,14);   // bar: after stage-in
        addg(P.s, 4, 8, 0, 0,15, 0,16, -1,0);   // pivots {7,8,0}
        addg(P.s, 4, 8, 1, 0,17, 0,18, 0,19);
        addg(P.s, 4, 8, 1, 1,13, 1,14, 1,15);
        addg(P.s, 4, 8, 1, 1,16, 1,17, 1,18);
        addg(P.s, 4, 8, 1, 1,19, 2,14, 2,15);   // pivots {11,6,7}
        addg(P.s, 4, 8, 1, 2,16, 2,17, 2,18);
        addg(P.s, 4, 8, 1, 2,19, 3,15, 3,16);   // pivots {11,7,8}
        addg(P.s, 4, 8, 1, 3,17, 3,18, 3,19);
    } else if (ph == 2) {
        // FIX (R9 bug): R6-verified packing -- all groups have DISTINCT
        // local pivots. R9's regroup had (1,12)&(2,12) both pivot 9 and
        // (2,13)&(3,13) both pivot 10 -> broken coset bijection.
        P.FL = 6; P.GAP = 3; P.fuse_in = 1; P.fuse_out = 0;  // [0,5]u[9,14]
        addg(P.s, 6, 3, 0, 1,0, 1,1, 1,2);      // fused into stage-in (contig)
        addg(P.s, 6, 3, 1, 1,3, 1,4, 1,5);      // bar: trigS guard
        addg(P.s, 6, 3, 1, 1,10, 1,11, 1,12);   // pivots {7,8,9} cross-wave
        addg(P.s, 6, 3, 1, 2,11, 2,12, 2,13);   // pivots {8,9,10}
        addg(P.s, 6, 3, 1, 3,12, 3,13, 3,14);   // pivots {9,10,11}
    } else {
        P.FL = 12; P.GAP = 8; P.fuse_in = 0; P.fuse_out = 1;
        addg(P.s, 12, 8, 1, 1,6, 1,7, 1,8);     // bar: after stage-in
        addg(P.s, 12, 8, 1, 1,9, 2,0, 2,1);
        addg(P.s, 12, 8, 1, 2,2, 2,3, 2,4);
        addg(P.s, 12, 8, 0, 2,5, 2,6, 2,7);
        addg(P.s, 12, 8, 1, 2,8, 2,9, 2,10);
        addg(P.s, 12, 8, 1, 3,3, 3,4, 3,5);
        addg(P.s, 12, 8, 0, 3,6, 3,7, 3,8);
        addg(P.s, 12, 8, 1, 3,9, 3,10, 3,11);
        addg(P.s, 12, 8, 1, 3,0, 3,1, 3,2);     // fused into stage-out (contig)
    }
    return P;
}

// Compile-time guard: coset bijection requires distinct top bits per group.
constexpr bool pivots_ok(int ph) {
    PhC P = mk_phase(ph);
    for (int i = 0; i < P.s.ng; ++i) {
        const GroupC& g = P.s.g[i];
        if (g.pv[0] == g.pv[1] || g.pv[1] == g.pv[2] || g.pv[0] == g.pv[2])
            return false;
    }
    return true;
}
static_assert(pivots_ok(0) && pivots_ok(1) && pivots_ok(2) && pivots_ok(3),
              "pivot collision: coset decomposition not bijective");

__device__ __forceinline__ unsigned swz(unsigned t) { return t ^ ((t >> 5) & 0xFu); }
__device__ __forceinline__ f32x2 splat2(float x) { f32x2 r = {x, x}; return r; }

template<int FL, int GAP>
__device__ __forceinline__ unsigned gmapF(unsigned t, unsigned mid) {
    if constexpr (FL == 12) return (mid << 12) | t;
    else return (t & ((1u << FL) - 1u)) | ((mid & ((1u << GAP) - 1u)) << FL)
              | ((t >> FL) << (FL + GAP)) | ((mid >> GAP) << (GAP + 12));
}

__device__ __forceinline__ unsigned expand3(unsigned u, int p0, int p1, int p2) {
    u = ((u >> p0) << (p0 + 1)) | (u & ((1u << p0) - 1u));
    u = ((u >> p1) << (p1 + 1)) | (u & ((1u << p1) - 1u));
    u = ((u >> p2) << (p2 + 1)) | (u & ((1u << p2) - 1u));
    return u;
}

__constant__ __device__ int BASE_TBL[3][4] = {{0, 2, 4, 6}, {0, 1, 4, 5}, {0, 1, 2, 3}};

// 3 butterflies on an 8-amp register coset. G must constant-fold.
#define APPLY_GROUP(G, v, g0, cd, sd)                                           \
    {                                                                            \
        _Pragma("unroll")                                                        \
        for (int j = 0; j < 3; ++j) {                                            \
            if ((G).gt[j].valid) {                                               \
                const f32x2 cc_ = splat2((cd)[j]);                               \
                const unsigned par_ = (unsigned)__popc((g0) & (G).gt[j].R) & 1u; \
                const float sp_ = par_ ? (sd)[j] : -(sd)[j];                     \
                _Pragma("unroll")                                                \
                for (int pr = 0; pr < 4; ++pr) {                                 \
                    const int ea = BASE_TBL[j][pr];                              \
                    const int eb = ea | (1 << j);                                \
                    const f32x2 sg_ = splat2((((G).gt[j].sb >> ea) & 1u) ? -sp_ : sp_); \
                    const f32x2 a_ = v[ea], b_ = v[eb];                          \
                    v[ea] = cc_ * a_ + sg_ * b_;                                 \
                    v[eb] = cc_ * b_ - sg_ * a_;                                 \
                }                                                                \
            }                                                                    \
        }                                                                        \
    }

// ================= phase kernel =================
// 4096-amp LDS tile; 512 threads x 8-amp cosets. Stage ends fused ONLY for
// contiguous {bits 0,1,2}-span groups; otherwise plain coalesced copies.
template<int PH, bool IS_INIT, bool IS_FINAL>
__global__ __launch_bounds__(512) void k_phase(f32x2* __restrict__ st,
                                               const float* __restrict__ qr,
                                               const float* __restrict__ qi,
                                               const float* __restrict__ theta,
                                               float* __restrict__ out) {
    constexpr PhC P = mk_phase(PH);
    constexpr int FL = P.FL, GAP = P.GAP, NG = P.s.ng;
    __shared__ __align__(16) f32x2 lds[4096];
    __shared__ float2 trigS[80];
    f32x4* lds4 = reinterpret_cast<f32x4*>(lds);
    const unsigned tid = threadIdx.x;
    const unsigned mid = blockIdx.x;

    if (tid < 80) {
        int l = tid / NQ, b = tid % NQ;
        float th = 0.5f * theta[l * NQ + (NQ - 1 - b)];
        trigS[tid] = make_float2(cosf(th), sinf(th));
    }

    // ---- stage-in ----
    if constexpr (P.fuse_in) {
        constexpr GroupC G = P.s.g[0];
        const unsigned t0 = tid << 3;                 // pivots {0,1,2}
        const unsigned g0 = gmapF<FL, GAP>(t0, mid);
        f32x2 v[8];
        if constexpr (IS_INIT) {
            const f32x4* r4 = reinterpret_cast<const f32x4*>(qr);
            const f32x4* i4 = reinterpret_cast<const f32x4*>(qi);
            f32x4 ra = r4[g0 >> 2], rb = r4[(g0 >> 2) + 1];
            f32x4 ia = i4[g0 >> 2], ib = i4[(g0 >> 2) + 1];
            const float re[8] = {ra.x, ra.y, ra.z, ra.w, rb.x, rb.y, rb.z, rb.w};
            const float im[8] = {ia.x, ia.y, ia.z, ia.w, ib.x, ib.y, ib.z, ib.w};
#pragma unroll
            for (int e = 0; e < 8; ++e) v[e] = f32x2{re[G.gxs[e] & 7u], im[G.gxs[e] & 7u]};
        } else {
            const f32x4* s4 = reinterpret_cast<const f32x4*>(st);
            f32x4 q[4];
#pragma unroll
            for (int k = 0; k < 4; ++k) q[k] = s4[(g0 >> 1) + k];
            const float* qq = reinterpret_cast<const float*>(q);
#pragma unroll
            for (int e = 0; e < 8; ++e) {
                const unsigned j = G.gxs[e] & 7u;
                v[e] = f32x2{qq[2 * j], qq[2 * j + 1]};
            }
        }
        float cd[3], sd[3];
#pragma unroll
        for (int j = 0; j < 3; ++j)
            if (G.gt[j].valid) {
                float th = 0.5f * theta[G.gt[j].thix];
                cd[j] = cosf(th); sd[j] = sinf(th);
            }
        APPLY_GROUP(G, v, g0, cd, sd);
#pragma unroll
        for (int e = 0; e < 8; ++e) lds[swz(t0 ^ G.lgxs[e])] = v[e];
        // fused stage-in writes only this wave's region -> no barrier here;
        // first round's bar flag (trigS guard) provides the sync.
    } else {
        const f32x4* s4 = reinterpret_cast<const f32x4*>(st);
#pragma unroll
        for (int k = 0; k < 4; ++k) {
            unsigned u4 = tid + (unsigned)(k << 9);   // 2 amps (interleaved)
            unsigned t = u4 << 1;
            unsigned g = gmapF<FL, GAP>(t, mid);
            f32x4 d = s4[g >> 1];
            unsigned sw = swz(t);
            f32x4 e = (sw & 1u) ? __builtin_shufflevector(d, d, 2, 3, 0, 1) : d;
            lds4[sw >> 1] = e;
        }
        // cross-wave writes -> first round's bar flag is 1 (syncthreads).
    }

    // ---- in-LDS rounds ----
    constexpr int GI0 = P.fuse_in ? 1 : 0;
    constexpr int GI1 = P.fuse_out ? NG - 1 : NG;
#pragma unroll
    for (int gi = GI0; gi < GI1; ++gi) {
        if (P.s.bar[gi]) __syncthreads();
        else __builtin_amdgcn_wave_barrier();
        const unsigned t0 = expand3(tid, P.s.g[gi].pv[0], P.s.g[gi].pv[1], P.s.g[gi].pv[2]);
        const unsigned g0 = gmapF<FL, GAP>(t0, mid);
        const unsigned sz0 = swz(t0);
        f32x2 v[8]; unsigned ad[8];
#pragma unroll
        for (int e = 0; e < 8; ++e) {
            ad[e] = sz0 ^ cswz(P.s.g[gi].lgxs[e]);    // folds to immediate XOR
            v[e] = lds[ad[e]];
        }
        float cd[3], sd[3];
#pragma unroll
        for (int j = 0; j < 3; ++j)
            if (P.s.g[gi].gt[j].valid) {
                float2 cs = trigS[P.s.g[gi].gt[j].tix];
                cd[j] = cs.x; sd[j] = cs.y;
            }
        APPLY_GROUP(P.s.g[gi], v, g0, cd, sd);
#pragma unroll
        for (int e = 0; e < 8; ++e) lds[ad[e]] = v[e];
    }

    __syncthreads();

    // ---- stage-out ----
    if constexpr (P.fuse_out) {
        constexpr GroupC G = P.s.g[NG - 1];
        const unsigned t0 = tid << 3;                 // pivots {0,1,2}
        const unsigned g0 = gmapF<FL, GAP>(t0, mid);
        f32x2 v[8];
#pragma unroll
        for (int e = 0; e < 8; ++e) v[e] = lds[swz(t0 ^ G.lgxs[e])];
        float cd[3], sd[3];
#pragma unroll
        for (int j = 0; j < 3; ++j)
            if (G.gt[j].valid) {
                float2 cs = trigS[G.gt[j].tix];
                cd[j] = cs.x; sd[j] = cs.y;
            }
        APPLY_GROUP(G, v, g0, cd, sd);
        if constexpr (IS_FINAL) {
            // out[ginv4(g0 ^ gxs[e])] = v[e]; ginv4 identity on bits [0,2]
            // cosets -> the 8 outputs fill the aligned block of i0 = ginv4(g0).
            // base = i0&~7, slot q = (i0&7) ^ (gxs[e]&7).
            const unsigned i0 = g0 ^ (g0 >> 4) ^ (g0 >> 8) ^ (g0 >> 12) ^ (g0 >> 16);
            const unsigned base = i0 & ~7u;
            const unsigned lo = i0 & 7u;
            f32x2 u[8];
#pragma unroll
            for (int e = 0; e < 8; ++e) u[G.gxs[e] & 7u] = v[e];   // static perm
            // XOR-permute u by lo via 3 predicated swap layers (no scratch):
#pragma unroll
            for (int bit = 1; bit <= 4; bit <<= 1) {
                const bool c = (lo & (unsigned)bit) != 0u;
                f32x2 t[8];
#pragma unroll
                for (int k = 0; k < 8; ++k) t[k] = c ? u[k ^ bit] : u[k];
#pragma unroll
                for (int k = 0; k < 8; ++k) u[k] = t[k];
            }
            float4* oR = reinterpret_cast<float4*>(out + base);
            float4* oI = reinterpret_cast<float4*>(out + DIM + base);
            oR[0] = make_float4(u[0].x, u[1].x, u[2].x, u[3].x);
            oR[1] = make_float4(u[4].x, u[5].x, u[6].x, u[7].x);
            oI[0] = make_float4(u[0].y, u[1].y, u[2].y, u[3].y);
            oI[1] = make_float4(u[4].y, u[5].y, u[6].y, u[7].y);
        } else {
            f32x4* s4 = reinterpret_cast<f32x4*>(st);
            float so[16];
#pragma unroll
            for (int e = 0; e < 8; ++e) {
                const unsigned j = G.gxs[e] & 7u;
                so[2 * j] = v[e].x; so[2 * j + 1] = v[e].y;
            }
#pragma unroll
            for (int k = 0; k < 4; ++k)
                s4[(g0 >> 1) + k] = f32x4{so[4 * k], so[4 * k + 1], so[4 * k + 2], so[4 * k + 3]};
        }
    } else {
        f32x4* s4 = reinterpret_cast<f32x4*>(st);
#pragma unroll
        for (int k = 0; k < 4; ++k) {
            unsigned u4 = tid + (unsigned)(k << 9);
            unsigned t = u4 << 1;
            unsigned g = gmapF<FL, GAP>(t, mid);
            unsigned sw = swz(t);
            f32x4 e = lds4[sw >> 1];
            f32x4 d = (sw & 1u) ? __builtin_shufflevector(e, e, 2, 3, 0, 1) : e;
            s4[g >> 1] = d;
        }
    }
}

// ================= launch =================
extern "C" void kernel_launch(void* const* d_in, const int* in_sizes, int n_in,
                              void* d_out, int out_size, void* d_ws, size_t ws_size,
                              hipStream_t stream) {
    const float* theta = (const float*)d_in[0];   // (4,20) float32
    const float* qr    = (const float*)d_in[1];
    const float* qi    = (const float*)d_in[2];
    float* out = (float*)d_out;
    f32x2* st = (f32x2*)d_ws;                     // 8 MiB interleaved state

    k_phase<0, true,  false><<<256, 512, 0, stream>>>(st, qr, qi, theta, out);
    k_phase<1, false, false><<<256, 512, 0, stream>>>(st, qr, qi, theta, out);
    k_phase<2, false, false><<<256, 512, 0, stream>>>(st, qr, qi, theta, out);
    k_phase<3, false, true ><<<256, 512, 0, stream>>>(st, qr, qi, theta, out);
}

// Round 11
// 61.587 us; speedup vs baseline: 1.1011x; 1.0268x over previous
//
#include <hip/hip_runtime.h>
#include <cstdint>

#define NQ 20
#define DIM (1u << NQ)

typedef float f32x2 __attribute__((ext_vector_type(2)));
typedef float f32x4 __attribute__((ext_vector_type(4)));

// ================= constexpr GF(2) machinery =================
// Gray map g(x)=x^(x>>1) accumulates per CNOT-chain layer. Gate (l,b) is a
// butterfly with mask m=g^l(e_b) (span [b-l,b]) and selector parity(j&R),
// R = row b of g^{-l}. Final gather: out[ginv4(j)] = buf[j].
constexpr unsigned cpair_mask(int l, int b) {
    unsigned m = 1u << b;
    for (int k = 0; k < l; ++k) m ^= m >> 1;
    return m;
}
constexpr unsigned cginv1(unsigned x) {
    x ^= x >> 1; x ^= x >> 2; x ^= x >> 4; x ^= x >> 8; x ^= x >> 16;
    return x & 0xFFFFFu;
}
constexpr unsigned csel_mask(int l, int b) {
    unsigned R = 0;
    for (int k = 0; k < NQ; ++k) {
        unsigned w = 1u << k;
        for (int t = 0; t < l; ++t) w = cginv1(w);
        if ((w >> b) & 1u) R |= 1u << k;
    }
    return R;
}
constexpr int cpopc(unsigned x) { int c = 0; while (x) { c += x & 1; x >>= 1; } return c; }
constexpr unsigned cswz(unsigned t) { return t ^ ((t >> 5) & 0xFu); }

struct GateC { unsigned R; unsigned sb; int valid; int tix; int thix; };
struct GroupC { int pv[3]; unsigned gxs[8]; unsigned lgxs[8]; GateC gt[3]; };
struct SchedC { GroupC g[12]; int bar[12]; int ng; };
struct PhC { SchedC s; int FL, GAP; };

// local tile bits: [0,FL) global-direct, [FL,12) map to global [FL+GAP, GAP+12)
constexpr unsigned to_local(unsigned m, int FL, int GAP) {
    return (m & ((1u << FL) - 1u)) | ((m >> (FL + GAP)) << FL);
}

constexpr void addg(SchedC& s, int FL, int GAP, int bar,
                    int l0, int b0, int l1, int b1, int l2, int b2) {
    GroupC g{};
    int ls[3] = {l0, l1, l2}; int bs[3] = {b0, b1, b2};
    unsigned m[3] = {0, 0, 0};
    for (int j = 0; j < 3; ++j) {
        bool val = ls[j] >= 0;
        m[j] = val ? cpair_mask(ls[j], bs[j]) : (1u << bs[j]);   // pad: plain bit
        g.gt[j].R = val ? csel_mask(ls[j], bs[j]) : 0u;
        g.gt[j].valid = val ? 1 : 0;
        g.gt[j].tix = val ? (ls[j] * NQ + bs[j]) : 0;
        g.gt[j].thix = val ? (ls[j] * NQ + (NQ - 1 - bs[j])) : 0;
    }
    for (int e = 0; e < 8; ++e) {
        unsigned x = 0;
        for (int j = 0; j < 3; ++j) if ((e >> j) & 1) x ^= m[j];
        g.gxs[e] = x;
        g.lgxs[e] = to_local(x, FL, GAP);
    }
    for (int j = 0; j < 3; ++j) {
        unsigned sb = 0;
        for (int e = 0; e < 8; ++e) if (cpopc(g.gxs[e] & g.gt[j].R) & 1) sb |= (1u << e);
        g.gt[j].sb = sb;
    }
    int pv[3] = {0, 0, 0};
    for (int j = 0; j < 3; ++j) {
        unsigned lm = to_local(m[j], FL, GAP);
        int p = 0; for (int k = 0; k < 12; ++k) if ((lm >> k) & 1) p = k;
        pv[j] = p;
    }
    for (int a = 0; a < 2; ++a)
        for (int c = 0; c < 2 - a; ++c)
            if (pv[c] > pv[c + 1]) { int t = pv[c]; pv[c] = pv[c + 1]; pv[c + 1] = t; }
    g.pv[0] = pv[0]; g.pv[1] = pv[1]; g.pv[2] = pv[2];
    s.bar[s.ng] = bar;
    s.g[s.ng] = g; s.ng++;
}

// 4-phase schedule (R10-verified gate ORDER, collision-free packing), with
// ALL stage ends fused (group 0 -> stage-in, group ng-1 -> stage-out).
// bar=1: __syncthreads before in-LDS round; bar=0: this round AND the
// previous are wave-local (all pivots <= 8; wave id = t0 bits 9-11,
// preserved by swz) -> wave_barrier suffices.
constexpr PhC mk_phase(int ph) {
    PhC P{};
    if (ph == 0) {
        P.FL = 12; P.GAP = 8;
        addg(P.s, 12, 8, 0, 0,0, 0,1, 0,2);     // fused-in (contig, IS_INIT)
        addg(P.s, 12, 8, 1, 0,3, 0,4, 0,5);     // bar: trigS/stage guard
        addg(P.s, 12, 8, 0, 0,6, 0,7, 0,8);     // wave-local after wave-local
        addg(P.s, 12, 8, 1, 0,9, 0,10, 0,11);   // fused-out (scatter)
    } else if (ph == 1) {
        P.FL = 4; P.GAP = 8;                    // window [0,3] u [12,19]
        addg(P.s, 4, 8, 0, 0,12, 0,13, 0,14);   // fused-in (scatter)
        addg(P.s, 4, 8, 1, 0,15, 0,16, 0,17);
        addg(P.s, 4, 8, 1, 0,18, 0,19, 1,13);
        addg(P.s, 4, 8, 1, 1,14, 1,15, 1,16);
        addg(P.s, 4, 8, 1, 1,17, 1,18, 1,19);
        addg(P.s, 4, 8, 1, 2,14, 2,15, 2,16);
        addg(P.s, 4, 8, 1, 2,17, 2,18, 2,19);
        addg(P.s, 4, 8, 1, 3,15, 3,16, -1,0);   // 1 pad (pivot 0)
        addg(P.s, 4, 8, 1, 3,17, 3,18, 3,19);   // fused-out (scatter)
    } else if (ph == 2) {
        P.FL = 6; P.GAP = 3;                    // window [0,5] u [9,14]
        addg(P.s, 6, 3, 0, 1,0, 1,1, 1,2);      // fused-in (contig)
        addg(P.s, 6, 3, 1, 1,3, 1,4, 1,5);
        addg(P.s, 6, 3, 1, 1,10, 1,11, 1,12);   // pivots {7,8,9}
        addg(P.s, 6, 3, 1, 2,11, 2,12, 2,13);   // pivots {8,9,10}
        addg(P.s, 6, 3, 1, 3,12, 3,13, 3,14);   // fused-out (scatter) {9,10,11}
    } else {
        P.FL = 12; P.GAP = 8;
        addg(P.s, 12, 8, 0, 1,6, 1,7, 1,8);     // fused-in (scatter)
        addg(P.s, 12, 8, 1, 1,9, 2,0, 2,1);
        addg(P.s, 12, 8, 1, 2,2, 2,3, 2,4);
        addg(P.s, 12, 8, 0, 2,5, 2,6, 2,7);     // wave-local after wave-local
        addg(P.s, 12, 8, 1, 2,8, 2,9, 2,10);
        addg(P.s, 12, 8, 1, 3,3, 3,4, 3,5);
        addg(P.s, 12, 8, 0, 3,6, 3,7, 3,8);     // wave-local after wave-local
        addg(P.s, 12, 8, 1, 3,9, 3,10, 3,11);
        addg(P.s, 12, 8, 1, 3,0, 3,1, 3,2);     // fused-out -> IS_FINAL gather
    }
    return P;
}

// ---- compile-time guards ----
// (1) coset bijection: distinct local pivots per group (R9's bug class).
constexpr bool pivots_ok(int ph) {
    PhC P = mk_phase(ph);
    for (int i = 0; i < P.s.ng; ++i) {
        const GroupC& g = P.s.g[i];
        if (g.pv[0] == g.pv[1] || g.pv[1] == g.pv[2] || g.pv[0] == g.pv[2])
            return false;
    }
    return true;
}
// (2) window containment: every coset offset must round-trip local<->global.
constexpr bool window_ok(int ph) {
    PhC P = mk_phase(ph);
    for (int i = 0; i < P.s.ng; ++i)
        for (int e = 0; e < 8; ++e) {
            unsigned lm = P.s.g[i].lgxs[e];
            unsigned inv = (lm & ((1u << P.FL) - 1u)) | ((lm >> P.FL) << (P.FL + P.GAP));
            if (inv != P.s.g[i].gxs[e]) return false;
        }
    return true;
}
static_assert(pivots_ok(0) && pivots_ok(1) && pivots_ok(2) && pivots_ok(3),
              "pivot collision: coset decomposition not bijective");
static_assert(window_ok(0) && window_ok(1) && window_ok(2) && window_ok(3),
              "gate mask outside phase window");

constexpr unsigned max_gxs(const GroupC& g) {
    unsigned m = 0;
    for (int e = 0; e < 8; ++e) if (g.gxs[e] > m) m = g.gxs[e];
    return m;
}

__device__ __forceinline__ unsigned swz(unsigned t) { return t ^ ((t >> 5) & 0xFu); }
__device__ __forceinline__ f32x2 splat2(float x) { f32x2 r = {x, x}; return r; }

template<int FL, int GAP>
__device__ __forceinline__ unsigned gmapF(unsigned t, unsigned mid) {
    if constexpr (FL == 12) return (mid << 12) | t;
    else return (t & ((1u << FL) - 1u)) | ((mid & ((1u << GAP) - 1u)) << FL)
              | ((t >> FL) << (FL + GAP)) | ((mid >> GAP) << (GAP + 12));
}

__device__ __forceinline__ unsigned expand3(unsigned u, int p0, int p1, int p2) {
    u = ((u >> p0) << (p0 + 1)) | (u & ((1u << p0) - 1u));
    u = ((u >> p1) << (p1 + 1)) | (u & ((1u << p1) - 1u));
    u = ((u >> p2) << (p2 + 1)) | (u & ((1u << p2) - 1u));
    return u;
}

__constant__ __device__ int BASE_TBL[3][4] = {{0, 2, 4, 6}, {0, 1, 4, 5}, {0, 1, 2, 3}};

// 3 butterflies on an 8-amp register coset. G must constant-fold.
#define APPLY_GROUP(G, v, g0, cd, sd)                                           \
    {                                                                            \
        _Pragma("unroll")                                                        \
        for (int j = 0; j < 3; ++j) {                                            \
            if ((G).gt[j].valid) {                                               \
                const f32x2 cc_ = splat2((cd)[j]);                               \
                const unsigned par_ = (unsigned)__popc((g0) & (G).gt[j].R) & 1u; \
                const float sp_ = par_ ? (sd)[j] : -(sd)[j];                     \
                _Pragma("unroll")                                                \
                for (int pr = 0; pr < 4; ++pr) {                                 \
                    const int ea = BASE_TBL[j][pr];                              \
                    const int eb = ea | (1 << j);                                \
                    const f32x2 sg_ = splat2((((G).gt[j].sb >> ea) & 1u) ? -sp_ : sp_); \
                    const f32x2 a_ = v[ea], b_ = v[eb];                          \
                    v[ea] = cc_ * a_ + sg_ * b_;                                 \
                    v[eb] = cc_ * b_ - sg_ * a_;                                 \
                }                                                                \
            }                                                                    \
        }                                                                        \
    }

// ================= phase kernel =================
// 4096-amp LDS tile; 512 threads x 8-amp cosets; group 0 fused into
// stage-in, group ng-1 into stage-out (contiguous path when coset spans
// bits {0,1,2}, else 8B gather/scatter).
template<int PH, bool IS_INIT, bool IS_FINAL>
__global__ __launch_bounds__(512) void k_phase(f32x2* __restrict__ st,
                                               const float* __restrict__ qr,
                                               const float* __restrict__ qi,
                                               const float* __restrict__ theta,
                                               float* __restrict__ out) {
    constexpr PhC P = mk_phase(PH);
    constexpr int FL = P.FL, GAP = P.GAP, NG = P.s.ng;
    __shared__ __align__(16) f32x2 lds[4096];
    __shared__ float2 trigS[80];
    const unsigned tid = threadIdx.x;
    const unsigned mid = blockIdx.x;

    if (tid < 80) {
        int l = tid / NQ, b = tid % NQ;
        float th = 0.5f * theta[l * NQ + (NQ - 1 - b)];
        trigS[tid] = make_float2(cosf(th), sinf(th));
    }

    // ---- stage-in, fused group 0 ----
    {
        constexpr GroupC G = P.s.g[0];
        constexpr bool CIN = (max_gxs(G) < 8u);   // coset = 8 contiguous amps
        const unsigned t0 = expand3(tid, G.pv[0], G.pv[1], G.pv[2]);
        const unsigned g0 = gmapF<FL, GAP>(t0, mid);
        f32x2 v[8];
        if constexpr (IS_INIT) {
            const f32x4* r4 = reinterpret_cast<const f32x4*>(qr);
            const f32x4* i4 = reinterpret_cast<const f32x4*>(qi);
            f32x4 ra = r4[g0 >> 2], rb = r4[(g0 >> 2) + 1];
            f32x4 ia = i4[g0 >> 2], ib = i4[(g0 >> 2) + 1];
            const float re[8] = {ra.x, ra.y, ra.z, ra.w, rb.x, rb.y, rb.z, rb.w};
            const float im[8] = {ia.x, ia.y, ia.z, ia.w, ib.x, ib.y, ib.z, ib.w};
#pragma unroll
            for (int e = 0; e < 8; ++e) v[e] = f32x2{re[G.gxs[e] & 7u], im[G.gxs[e] & 7u]};
        } else if constexpr (CIN) {
            const f32x4* s4 = reinterpret_cast<const f32x4*>(st);
            f32x4 q[4];
#pragma unroll
            for (int k = 0; k < 4; ++k) q[k] = s4[(g0 >> 1) + k];
            const float* qq = reinterpret_cast<const float*>(q);
#pragma unroll
            for (int e = 0; e < 8; ++e) {
                const unsigned j = G.gxs[e] & 7u;
                v[e] = f32x2{qq[2 * j], qq[2 * j + 1]};
            }
        } else {
#pragma unroll
            for (int e = 0; e < 8; ++e) v[e] = st[g0 ^ G.gxs[e]];
        }
        float cd[3], sd[3];
#pragma unroll
        for (int j = 0; j < 3; ++j)
            if (G.gt[j].valid) {
                float th = 0.5f * theta[G.gt[j].thix];
                cd[j] = cosf(th); sd[j] = sinf(th);
            }
        APPLY_GROUP(G, v, g0, cd, sd);
#pragma unroll
        for (int e = 0; e < 8; ++e) lds[swz(t0 ^ G.lgxs[e])] = v[e];
        // first in-LDS round has bar=1 -> provides the trigS/stage sync.
    }

    // ---- in-LDS rounds: groups 1 .. NG-2 ----
#pragma unroll
    for (int gi = 1; gi < NG - 1; ++gi) {
        if (P.s.bar[gi]) __syncthreads();
        else __builtin_amdgcn_wave_barrier();
        const unsigned t0 = expand3(tid, P.s.g[gi].pv[0], P.s.g[gi].pv[1], P.s.g[gi].pv[2]);
        const unsigned g0 = gmapF<FL, GAP>(t0, mid);
        const unsigned sz0 = swz(t0);
        f32x2 v[8]; unsigned ad[8];
#pragma unroll
        for (int e = 0; e < 8; ++e) {
            ad[e] = sz0 ^ cswz(P.s.g[gi].lgxs[e]);    // folds to immediate XOR
            v[e] = lds[ad[e]];
        }
        float cd[3], sd[3];
#pragma unroll
        for (int j = 0; j < 3; ++j)
            if (P.s.g[gi].gt[j].valid) {
                float2 cs = trigS[P.s.g[gi].gt[j].tix];
                cd[j] = cs.x; sd[j] = cs.y;
            }
        APPLY_GROUP(P.s.g[gi], v, g0, cd, sd);
#pragma unroll
        for (int e = 0; e < 8; ++e) lds[ad[e]] = v[e];
    }

    __syncthreads();

    // ---- stage-out, fused group NG-1 ----
    {
        constexpr GroupC G = P.s.g[NG - 1];
        const unsigned t0 = expand3(tid, G.pv[0], G.pv[1], G.pv[2]);
        const unsigned g0 = gmapF<FL, GAP>(t0, mid);
        f32x2 v[8];
#pragma unroll
        for (int e = 0; e < 8; ++e) v[e] = lds[swz(t0 ^ G.lgxs[e])];
        float cd[3], sd[3];
#pragma unroll
        for (int j = 0; j < 3; ++j)
            if (G.gt[j].valid) {
                float2 cs = trigS[G.gt[j].tix];
                cd[j] = cs.x; sd[j] = cs.y;
            }
        APPLY_GROUP(G, v, g0, cd, sd);
        if constexpr (IS_FINAL) {
            // out[ginv4(g0 ^ gxs[e])]: ginv4 identity on bits 0-2 cosets ->
            // 8 outputs fill the aligned block of i0 = ginv4(g0).
            const unsigned i0 = g0 ^ (g0 >> 4) ^ (g0 >> 8) ^ (g0 >> 12) ^ (g0 >> 16);
            const unsigned base = i0 & ~7u;
            const unsigned lo = i0 & 7u;
            f32x2 u[8];
#pragma unroll
            for (int e = 0; e < 8; ++e) u[G.gxs[e] & 7u] = v[e];   // static perm
#pragma unroll
            for (int bit = 1; bit <= 4; bit <<= 1) {               // XOR-perm by lo
                const bool c = (lo & (unsigned)bit) != 0u;
                f32x2 t[8];
#pragma unroll
                for (int k = 0; k < 8; ++k) t[k] = c ? u[k ^ bit] : u[k];
#pragma unroll
                for (int k = 0; k < 8; ++k) u[k] = t[k];
            }
            float4* oR = reinterpret_cast<float4*>(out + base);
            float4* oI = reinterpret_cast<float4*>(out + DIM + base);
            oR[0] = make_float4(u[0].x, u[1].x, u[2].x, u[3].x);
            oR[1] = make_float4(u[4].x, u[5].x, u[6].x, u[7].x);
            oI[0] = make_float4(u[0].y, u[1].y, u[2].y, u[3].y);
            oI[1] = make_float4(u[4].y, u[5].y, u[6].y, u[7].y);
        } else {
#pragma unroll
            for (int e = 0; e < 8; ++e) st[g0 ^ G.gxs[e]] = v[e];
        }
    }
}

// ================= launch =================
extern "C" void kernel_launch(void* const* d_in, const int* in_sizes, int n_in,
                              void* d_out, int out_size, void* d_ws, size_t ws_size,
                              hipStream_t stream) {
    const float* theta = (const float*)d_in[0];   // (4,20) float32
    const float* qr    = (const float*)d_in[1];
    const float* qi    = (const float*)d_in[2];
    float* out = (float*)d_out;
    f32x2* st = (f32x2*)d_ws;                     // 8 MiB interleaved state

    k_phase<0, true,  false><<<256, 512, 0, stream>>>(st, qr, qi, theta, out);
    k_phase<1, false, false><<<256, 512, 0, stream>>>(st, qr, qi, theta, out);
    k_phase<2, false, false><<<256, 512, 0, stream>>>(st, qr, qi, theta, out);
    k_phase<3, false, true ><<<256, 512, 0, stream>>>(st, qr, qi, theta, out);
}

// Round 12
// 43.101 us; speedup vs baseline: 1.5734x; 1.4289x over previous
//
#include <hip/hip_runtime.h>
#include <cstdint>

#define NQ 20
#define DIM (1u << NQ)

typedef float f32x2 __attribute__((ext_vector_type(2)));
typedef float f32x4 __attribute__((ext_vector_type(4)));

// ================= constexpr GF(2) machinery =================
// Gray map g(x)=x^(x>>1) accumulates per CNOT-chain layer. Gate (l,b) is a
// butterfly with mask m=g^l(e_b) (span [b-l,b]) and selector parity(j&R),
// R = row b of g^{-l}. Commute iff parity(m1&R2)==parity(m2&R1).
// Final gather: out[ginv4(j)] = buf[j].
constexpr unsigned cpair_mask(int l, int b) {
    unsigned m = 1u << b;
    for (int k = 0; k < l; ++k) m ^= m >> 1;
    return m;
}
constexpr unsigned cginv1(unsigned x) {
    x ^= x >> 1; x ^= x >> 2; x ^= x >> 4; x ^= x >> 8; x ^= x >> 16;
    return x & 0xFFFFFu;
}
constexpr unsigned csel_mask(int l, int b) {
    unsigned R = 0;
    for (int k = 0; k < NQ; ++k) {
        unsigned w = 1u << k;
        for (int t = 0; t < l; ++t) w = cginv1(w);
        if ((w >> b) & 1u) R |= 1u << k;
    }
    return R;
}
constexpr unsigned cswz(unsigned t) { return t ^ ((t >> 5) & 0xFu); }

struct GateC { unsigned R; unsigned sb; int valid; int tix; int thix; };
struct GroupC { int pv[2]; unsigned gxs[4]; unsigned lgxs[4]; GateC gt[2]; };
struct SchedC { GroupC g[20]; int bar[20]; int ng; };
struct PhC { SchedC s; int FL, GAP; };

// local tile bits: [0,FL) global-direct, [FL,12) map to global [FL+GAP, GAP+12)
constexpr unsigned to_local(unsigned m, int FL, int GAP) {
    return (m & ((1u << FL) - 1u)) | ((m >> (FL + GAP)) << FL);
}

constexpr void addg(SchedC& s, int FL, int GAP, int bar,
                    int l0, int b0, int l1, int b1) {
    GroupC g{};
    int ls[2] = {l0, l1}; int bs[2] = {b0, b1};
    unsigned m[2] = {0, 0};
    for (int j = 0; j < 2; ++j) {
        bool val = ls[j] >= 0;
        m[j] = val ? cpair_mask(ls[j], bs[j]) : (1u << bs[j]);   // pad: plain bit
        g.gt[j].R = val ? csel_mask(ls[j], bs[j]) : 0u;
        g.gt[j].valid = val ? 1 : 0;
        g.gt[j].tix = val ? (ls[j] * NQ + bs[j]) : 0;
        g.gt[j].thix = val ? (ls[j] * NQ + (NQ - 1 - bs[j])) : 0;
    }
    for (int e = 0; e < 4; ++e) {
        unsigned x = ((e & 1) ? m[0] : 0u) ^ ((e & 2) ? m[1] : 0u);
        g.gxs[e] = x;
        g.lgxs[e] = to_local(x, FL, GAP);
    }
    for (int j = 0; j < 2; ++j) {
        unsigned sb = 0;
        for (int e = 0; e < 4; ++e)
            if (__builtin_popcount(g.gxs[e] & g.gt[j].R) & 1) sb |= (1u << e);
        g.gt[j].sb = sb;
    }
    int pv[2] = {0, 0};
    for (int j = 0; j < 2; ++j) {
        unsigned lm = to_local(m[j], FL, GAP);
        int p = 0; for (int k = 0; k < 12; ++k) if ((lm >> k) & 1) p = k;
        pv[j] = p;
    }
    if (pv[0] > pv[1]) { int t = pv[0]; pv[0] = pv[1]; pv[1] = t; }
    g.pv[0] = pv[0]; g.pv[1] = pv[1];
    s.bar[s.ng] = bar;
    s.g[s.ng] = g; s.ng++;
}

// 4-phase schedule (same gate->phase assignment as verified R10/R11), now
// 2-gate groups (4-amp cosets) for 1024-thread blocks = 16 waves/CU.
// bar=1: __syncthreads before in-LDS round; bar=0: this round AND the
// previous have all pivots <= 7 (wave owns an aligned 256-amp block,
// closed under swz) -> wave_barrier suffices. First in-LDS round always 1
// (trigS guard). Group 0 fused into stage-in, last group into stage-out.
constexpr PhC mk_phase(int ph) {
    PhC P{};
    if (ph == 0) {
        P.FL = 12; P.GAP = 8;
        addg(P.s, 12, 8, 0, 0,0, 0,1);      // fused-in (contig, IS_INIT)
        addg(P.s, 12, 8, 1, 0,2, 0,3);      // trigS guard
        addg(P.s, 12, 8, 0, 0,4, 0,5);
        addg(P.s, 12, 8, 0, 0,6, 0,7);
        addg(P.s, 12, 8, 1, 0,8, 0,9);
        addg(P.s, 12, 8, 1, 0,10, 0,11);    // fused-out (scatter)
    } else if (ph == 1) {
        P.FL = 4; P.GAP = 8;                // window [0,3] u [12,19]
        addg(P.s, 4, 8, 0, 0,12, 0,13);     // fused-in (scatter)
        addg(P.s, 4, 8, 1, 0,14, 0,15);
        addg(P.s, 4, 8, 1, 0,16, 0,17);
        addg(P.s, 4, 8, 1, 0,18, 0,19);
        addg(P.s, 4, 8, 1, 1,13, 1,14);
        addg(P.s, 4, 8, 1, 1,15, 1,16);
        addg(P.s, 4, 8, 1, 1,17, 1,18);
        addg(P.s, 4, 8, 1, 1,19, 2,14);     // pivots {11,6}
        addg(P.s, 4, 8, 1, 2,15, 2,16);
        addg(P.s, 4, 8, 1, 2,17, 2,18);
        addg(P.s, 4, 8, 1, 2,19, 3,15);     // pivots {11,7}
        addg(P.s, 4, 8, 1, 3,16, 3,17);
        addg(P.s, 4, 8, 1, 3,18, 3,19);     // fused-out (scatter)
    } else if (ph == 2) {
        P.FL = 6; P.GAP = 3;                // window [0,5] u [9,14]
        addg(P.s, 6, 3, 0, 1,10, 1,11);     // fused-in (scatter)
        addg(P.s, 6, 3, 1, 1,12, 2,11);     // pivots {9,8}
        addg(P.s, 6, 3, 1, 2,12, 2,13);
        addg(P.s, 6, 3, 1, 3,12, 3,13);
        addg(P.s, 6, 3, 1, 3,14, -1,0);     // fused-out (1 pad, bit 0)
    } else {
        P.FL = 12; P.GAP = 8;
        addg(P.s, 12, 8, 0, 1,0, 1,1);      // fused-in (contig)
        addg(P.s, 12, 8, 1, 1,2, 1,3);      // trigS guard
        addg(P.s, 12, 8, 0, 1,4, 1,5);
        addg(P.s, 12, 8, 0, 1,6, 1,7);
        addg(P.s, 12, 8, 1, 1,8, 1,9);
        addg(P.s, 12, 8, 1, 2,0, 2,1);      // prev cross-wave
        addg(P.s, 12, 8, 0, 2,2, 2,3);
        addg(P.s, 12, 8, 0, 2,4, 2,5);
        addg(P.s, 12, 8, 0, 2,6, 2,7);
        addg(P.s, 12, 8, 1, 2,8, 2,9);
        addg(P.s, 12, 8, 1, 2,10, 3,2);     // pivots {10,2}
        addg(P.s, 12, 8, 1, 3,3, 3,4);      // prev cross-wave
        addg(P.s, 12, 8, 0, 3,5, 3,6);
        addg(P.s, 12, 8, 1, 3,7, 3,8);      // pivot 8 cross-wave
        addg(P.s, 12, 8, 1, 3,9, 3,10);
        addg(P.s, 12, 8, 1, 3,11, -1,0);    // 1 pad (bit 0)
        addg(P.s, 12, 8, 1, 3,0, 3,1);      // fused-out -> IS_FINAL gather
    }
    return P;
}

// ---- compile-time guards ----
constexpr bool pivots_ok(int ph) {
    PhC P = mk_phase(ph);
    for (int i = 0; i < P.s.ng; ++i)
        if (P.s.g[i].pv[0] == P.s.g[i].pv[1]) return false;
    return true;
}
constexpr bool window_ok(int ph) {
    PhC P = mk_phase(ph);
    for (int i = 0; i < P.s.ng; ++i)
        for (int e = 0; e < 4; ++e) {
            unsigned lm = P.s.g[i].lgxs[e];
            unsigned inv = (lm & ((1u << P.FL) - 1u)) | ((lm >> P.FL) << (P.FL + P.GAP));
            if (inv != P.s.g[i].gxs[e]) return false;
        }
    return true;
}
// Full executed-order circuit equivalence: every pair executed out of
// circuit order (layer-major; within layer all Ry commute) must satisfy
// parity(m1&R2)==parity(m2&R1).
constexpr bool order_ok() {
    int el[96] = {}, eb[96] = {}; int n = 0;
    for (int ph = 0; ph < 4; ++ph) {
        PhC P = mk_phase(ph);
        for (int gi = 0; gi < P.s.ng; ++gi)
            for (int j = 0; j < 2; ++j)
                if (P.s.g[gi].gt[j].valid) {
                    el[n] = P.s.g[gi].gt[j].tix / NQ;
                    eb[n] = P.s.g[gi].gt[j].tix % NQ;
                    ++n;
                }
    }
    if (n != 80) return false;
    bool seen[80] = {};
    unsigned M[80] = {}, R[80] = {};
    for (int i = 0; i < n; ++i) {
        int idx = el[i] * NQ + eb[i];
        if (seen[idx]) return false;
        seen[idx] = true;
        M[i] = cpair_mask(el[i], eb[i]);
        R[i] = csel_mask(el[i], eb[i]);
    }
    for (int i = 0; i < n; ++i)
        for (int j = i + 1; j < n; ++j)
            if (el[i] > el[j]) {           // executed earlier, circuit later
                int p1 = __builtin_popcount(M[i] & R[j]) & 1;
                int p2 = __builtin_popcount(M[j] & R[i]) & 1;
                if (p1 != p2) return false;
            }
    return true;
}
static_assert(pivots_ok(0) && pivots_ok(1) && pivots_ok(2) && pivots_ok(3),
              "pivot collision: coset decomposition not bijective");
static_assert(window_ok(0) && window_ok(1) && window_ok(2) && window_ok(3),
              "gate mask outside phase window");
static_assert(order_ok(), "executed gate order not circuit-equivalent");

constexpr unsigned max_gxs(const GroupC& g) {
    unsigned m = 0;
    for (int e = 0; e < 4; ++e) if (g.gxs[e] > m) m = g.gxs[e];
    return m;
}

__device__ __forceinline__ unsigned swz(unsigned t) { return t ^ ((t >> 5) & 0xFu); }
__device__ __forceinline__ f32x2 splat2(float x) { f32x2 r = {x, x}; return r; }

template<int FL, int GAP>
__device__ __forceinline__ unsigned gmapF(unsigned t, unsigned mid) {
    if constexpr (FL == 12) return (mid << 12) | t;
    else return (t & ((1u << FL) - 1u)) | ((mid & ((1u << GAP) - 1u)) << FL)
              | ((t >> FL) << (FL + GAP)) | ((mid >> GAP) << (GAP + 12));
}

__device__ __forceinline__ unsigned expand2(unsigned u, int p0, int p1) {
    u = ((u >> p0) << (p0 + 1)) | (u & ((1u << p0) - 1u));
    u = ((u >> p1) << (p1 + 1)) | (u & ((1u << p1) - 1u));
    return u;
}

// 2 butterflies on a 4-amp register coset. G must constant-fold.
#define APPLY_GROUP(G, v, g0, cd, sd)                                           \
    {                                                                            \
        _Pragma("unroll")                                                        \
        for (int j = 0; j < 2; ++j) {                                            \
            if ((G).gt[j].valid) {                                               \
                const f32x2 cc_ = splat2((cd)[j]);                               \
                const unsigned par_ = (unsigned)__popc((g0) & (G).gt[j].R) & 1u; \
                const float sp_ = par_ ? (sd)[j] : -(sd)[j];                     \
                _Pragma("unroll")                                                \
                for (int pr = 0; pr < 2; ++pr) {                                 \
                    const int ea = (j == 0) ? (pr << 1) : pr;                    \
                    const int eb = ea | (1 << j);                                \
                    const f32x2 sg_ = splat2((((G).gt[j].sb >> ea) & 1u) ? -sp_ : sp_); \
                    const f32x2 a_ = v[ea], b_ = v[eb];                          \
                    v[ea] = cc_ * a_ + sg_ * b_;                                 \
                    v[eb] = cc_ * b_ - sg_ * a_;                                 \
                }                                                                \
            }                                                                    \
        }                                                                        \
    }

// ================= phase kernel =================
// 4096-amp LDS tile; 1024 threads x 4-amp cosets (16 waves/CU); group 0
// fused into stage-in, last group into stage-out.
template<int PH, bool IS_INIT, bool IS_FINAL>
__global__ __launch_bounds__(1024) void k_phase(f32x2* __restrict__ st,
                                                const float* __restrict__ qr,
                                                const float* __restrict__ qi,
                                                const float* __restrict__ theta,
                                                float* __restrict__ out) {
    constexpr PhC P = mk_phase(PH);
    constexpr int FL = P.FL, GAP = P.GAP, NG = P.s.ng;
    __shared__ __align__(16) f32x2 lds[4096];
    __shared__ float2 trigS[80];
    const unsigned tid = threadIdx.x;
    const unsigned mid = blockIdx.x;

    if (tid < 80) {
        int l = tid / NQ, b = tid % NQ;
        float th = 0.5f * theta[l * NQ + (NQ - 1 - b)];
        trigS[tid] = make_float2(cosf(th), sinf(th));
    }

    // ---- stage-in, fused group 0 ----
    {
        constexpr GroupC G = P.s.g[0];
        constexpr bool CIN = (max_gxs(G) < 4u);   // coset = 4 contiguous amps
        const unsigned t0 = expand2(tid, G.pv[0], G.pv[1]);
        const unsigned g0 = gmapF<FL, GAP>(t0, mid);
        f32x2 v[4];
        if constexpr (IS_INIT) {
            const f32x4* r4 = reinterpret_cast<const f32x4*>(qr);
            const f32x4* i4 = reinterpret_cast<const f32x4*>(qi);
            f32x4 ra = r4[g0 >> 2], ia = i4[g0 >> 2];
            const float re[4] = {ra.x, ra.y, ra.z, ra.w};
            const float im[4] = {ia.x, ia.y, ia.z, ia.w};
#pragma unroll
            for (int e = 0; e < 4; ++e) v[e] = f32x2{re[G.gxs[e] & 3u], im[G.gxs[e] & 3u]};
        } else if constexpr (CIN) {
            const f32x4* s4 = reinterpret_cast<const f32x4*>(st);
            f32x4 q[2];
            q[0] = s4[g0 >> 1]; q[1] = s4[(g0 >> 1) + 1];
            const float* qq = reinterpret_cast<const float*>(q);
#pragma unroll
            for (int e = 0; e < 4; ++e) {
                const unsigned j = G.gxs[e] & 3u;
                v[e] = f32x2{qq[2 * j], qq[2 * j + 1]};
            }
        } else {
#pragma unroll
            for (int e = 0; e < 4; ++e) v[e] = st[g0 ^ G.gxs[e]];
        }
        float cd[2], sd[2];
#pragma unroll
        for (int j = 0; j < 2; ++j)
            if (G.gt[j].valid) {
                float th = 0.5f * theta[G.gt[j].thix];
                cd[j] = cosf(th); sd[j] = sinf(th);
            }
        APPLY_GROUP(G, v, g0, cd, sd);
#pragma unroll
        for (int e = 0; e < 4; ++e) lds[swz(t0 ^ G.lgxs[e])] = v[e];
        // first in-LDS round has bar=1 -> provides the trigS/stage sync.
    }

    // ---- in-LDS rounds: groups 1 .. NG-2 ----
#pragma unroll
    for (int gi = 1; gi < NG - 1; ++gi) {
        if (P.s.bar[gi]) __syncthreads();
        else __builtin_amdgcn_wave_barrier();
        const unsigned t0 = expand2(tid, P.s.g[gi].pv[0], P.s.g[gi].pv[1]);
        const unsigned g0 = gmapF<FL, GAP>(t0, mid);
        const unsigned sz0 = swz(t0);
        f32x2 v[4]; unsigned ad[4];
#pragma unroll
        for (int e = 0; e < 4; ++e) {
            ad[e] = sz0 ^ cswz(P.s.g[gi].lgxs[e]);    // folds to immediate XOR
            v[e] = lds[ad[e]];
        }
        float cd[2], sd[2];
#pragma unroll
        for (int j = 0; j < 2; ++j)
            if (P.s.g[gi].gt[j].valid) {
                float2 cs = trigS[P.s.g[gi].gt[j].tix];
                cd[j] = cs.x; sd[j] = cs.y;
            }
        APPLY_GROUP(P.s.g[gi], v, g0, cd, sd);
#pragma unroll
        for (int e = 0; e < 4; ++e) lds[ad[e]] = v[e];
    }

    __syncthreads();

    // ---- stage-out, fused group NG-1 ----
    {
        constexpr GroupC G = P.s.g[NG - 1];
        const unsigned t0 = expand2(tid, G.pv[0], G.pv[1]);
        const unsigned g0 = gmapF<FL, GAP>(t0, mid);
        f32x2 v[4];
#pragma unroll
        for (int e = 0; e < 4; ++e) v[e] = lds[swz(t0 ^ G.lgxs[e])];
        float cd[2], sd[2];
#pragma unroll
        for (int j = 0; j < 2; ++j)
            if (G.gt[j].valid) {
                float2 cs = trigS[G.gt[j].tix];
                cd[j] = cs.x; sd[j] = cs.y;
            }
        APPLY_GROUP(G, v, g0, cd, sd);
        if constexpr (IS_FINAL) {
            // out[ginv4(g0 ^ gxs[e])]: coset spans bits {0,1}; ginv4 is
            // identity on bits [0,1] -> outputs fill the 4-aligned block of
            // i0 = ginv4(g0). base = i0&~3, slot = (i0&3) ^ (gxs[e]&3).
            const unsigned i0 = g0 ^ (g0 >> 4) ^ (g0 >> 8) ^ (g0 >> 12) ^ (g0 >> 16);
            const unsigned base = i0 & ~3u;
            const unsigned lo = i0 & 3u;
            f32x2 u[4];
#pragma unroll
            for (int e = 0; e < 4; ++e) u[G.gxs[e] & 3u] = v[e];   // static perm
#pragma unroll
            for (int bit = 1; bit <= 2; bit <<= 1) {               // XOR-perm by lo
                const bool c = (lo & (unsigned)bit) != 0u;
                f32x2 t[4];
#pragma unroll
                for (int k = 0; k < 4; ++k) t[k] = c ? u[k ^ bit] : u[k];
#pragma unroll
                for (int k = 0; k < 4; ++k) u[k] = t[k];
            }
            float4* oR = reinterpret_cast<float4*>(out + base);
            float4* oI = reinterpret_cast<float4*>(out + DIM + base);
            oR[0] = make_float4(u[0].x, u[1].x, u[2].x, u[3].x);
            oI[0] = make_float4(u[0].y, u[1].y, u[2].y, u[3].y);
        } else {
#pragma unroll
            for (int e = 0; e < 4; ++e) st[g0 ^ G.gxs[e]] = v[e];
        }
    }
}

// ================= launch =================
extern "C" void kernel_launch(void* const* d_in, const int* in_sizes, int n_in,
                              void* d_out, int out_size, void* d_ws, size_t ws_size,
                              hipStream_t stream) {
    const float* theta = (const float*)d_in[0];   // (4,20) float32
    const float* qr    = (const float*)d_in[1];
    const float* qi    = (const float*)d_in[2];
    float* out = (float*)d_out;
    f32x2* st = (f32x2*)d_ws;                     // 8 MiB interleaved state

    k_phase<0, true,  false><<<256, 1024, 0, stream>>>(st, qr, qi, theta, out);
    k_phase<1, false, false><<<256, 1024, 0, stream>>>(st, qr, qi, theta, out);
    k_phase<2, false, false><<<256, 1024, 0, stream>>>(st, qr, qi, theta, out);
    k_phase<3, false, true ><<<256, 1024, 0, stream>>>(st, qr, qi, theta, out);
}

// Round 13
// 42.132 us; speedup vs baseline: 1.6096x; 1.0230x over previous
//
#include <hip/hip_runtime.h>
#include <cstdint>

#define NQ 20
#define DIM (1u << NQ)

typedef float f32x2 __attribute__((ext_vector_type(2)));
typedef float f32x4 __attribute__((ext_vector_type(4)));

// ================= constexpr GF(2) machinery =================
// Gray map g(x)=x^(x>>1) accumulates per CNOT-chain layer. Gate (l,b) is a
// butterfly with mask m=g^l(e_b) (span [b-l,b]) and selector parity(j&R),
// R = row b of g^{-l}. Commute iff parity(m1&R2)==parity(m2&R1).
// Triple identity: m(l,b-1)^m(l,b) = m(l+1,b) -> a rank-2 coset round can
// carry a third in-span gate (pair = element-index XOR 3).
// Final gather: out[ginv4(j)] = buf[j].
constexpr unsigned cpair_mask(int l, int b) {
    unsigned m = 1u << b;
    for (int k = 0; k < l; ++k) m ^= m >> 1;
    return m;
}
constexpr unsigned cginv1(unsigned x) {
    x ^= x >> 1; x ^= x >> 2; x ^= x >> 4; x ^= x >> 8; x ^= x >> 16;
    return x & 0xFFFFFu;
}
constexpr unsigned csel_mask(int l, int b) {
    unsigned R = 0;
    for (int k = 0; k < NQ; ++k) {
        unsigned w = 1u << k;
        for (int t = 0; t < l; ++t) w = cginv1(w);
        if ((w >> b) & 1u) R |= 1u << k;
    }
    return R;
}
constexpr unsigned cswz(unsigned t) { return t ^ ((t >> 5) & 0xFu); }

struct GateC { unsigned R; unsigned sb; int valid; int tix; int thix; };
struct GroupC { int pv[2]; unsigned gxs[4]; unsigned lgxs[4]; GateC gt[3]; unsigned m01[2]; };
struct SchedC { GroupC g[20]; int bar[20]; int ng; };
struct PhC { SchedC s; int FL, GAP; };

// local tile bits: [0,FL) global-direct, [FL,12) map to global [FL+GAP, GAP+12)
constexpr unsigned to_local(unsigned m, int FL, int GAP) {
    return (m & ((1u << FL) - 1u)) | ((m >> (FL + GAP)) << FL);
}

// slots: (l0,b0),(l1,b1) span the coset (l=-1: pad bit b for pivot);
// (l2,b2) optional third in-span gate with m2 == m0^m1 (l2=-1: none).
constexpr void addg(SchedC& s, int FL, int GAP, int bar,
                    int l0, int b0, int l1, int b1, int l2, int b2) {
    GroupC g{};
    int ls[3] = {l0, l1, l2}; int bs[3] = {b0, b1, b2};
    unsigned m[2] = {0, 0};
    for (int j = 0; j < 3; ++j) {
        bool val = ls[j] >= 0;
        if (j < 2) m[j] = val ? cpair_mask(ls[j], bs[j]) : (1u << bs[j]);
        g.gt[j].R = val ? csel_mask(ls[j], bs[j]) : 0u;
        g.gt[j].valid = val ? 1 : 0;
        g.gt[j].tix = val ? (ls[j] * NQ + bs[j]) : 0;
        g.gt[j].thix = val ? (ls[j] * NQ + (NQ - 1 - bs[j])) : 0;
    }
    g.m01[0] = m[0]; g.m01[1] = m[1];
    for (int e = 0; e < 4; ++e) {
        unsigned x = ((e & 1) ? m[0] : 0u) ^ ((e & 2) ? m[1] : 0u);
        g.gxs[e] = x;
        g.lgxs[e] = to_local(x, FL, GAP);
    }
    for (int j = 0; j < 3; ++j) {
        unsigned sb = 0;
        for (int e = 0; e < 4; ++e)
            if (__builtin_popcount(g.gxs[e] & g.gt[j].R) & 1) sb |= (1u << e);
        g.gt[j].sb = sb;
    }
    int pv[2] = {0, 0};
    for (int j = 0; j < 2; ++j) {
        unsigned lm = to_local(m[j], FL, GAP);
        int p = 0; for (int k = 0; k < 12; ++k) if ((lm >> k) & 1) p = k;
        pv[j] = p;
    }
    if (pv[0] > pv[1]) { int t = pv[0]; pv[0] = pv[1]; pv[1] = t; }
    g.pv[0] = pv[0]; g.pv[1] = pv[1];
    s.bar[s.ng] = bar;
    s.g[s.ng] = g; s.ng++;
}

// 4-phase schedule, triple-packed. bar=1: __syncthreads before in-LDS
// round; bar=0: this AND prev round wave-local (all pivots<=7; wave owns
// t0 bits[8,11], swz-closed). First in-LDS round bar=1 (trigS guard).
constexpr PhC mk_phase(int ph) {
    PhC P{};
    if (ph == 0) {
        P.FL = 12; P.GAP = 8;
        addg(P.s, 12, 8, 0, 0,0, 0,1, -1,0);     // fused-in (contig, INIT)
        addg(P.s, 12, 8, 1, 0,2, 0,3, -1,0);
        addg(P.s, 12, 8, 0, 0,4, 0,5, -1,0);
        addg(P.s, 12, 8, 0, 0,6, 0,7, -1,0);
        addg(P.s, 12, 8, 1, 0,8, 0,9, -1,0);
        addg(P.s, 12, 8, 1, 0,10, 0,11, -1,0);   // fused-out (scatter)
    } else if (ph == 1) {
        P.FL = 4; P.GAP = 8;                     // window [0,3] u [12,19]
        addg(P.s, 4, 8, 0, 0,12, 0,13, -1,0);    // fused-in (scatter)
        addg(P.s, 4, 8, 1, 0,14, 0,15, -1,0);
        addg(P.s, 4, 8, 1, 0,16, 0,17, -1,0);
        addg(P.s, 4, 8, 1, 0,18, 0,19, 1,19);    // A19 triple
        addg(P.s, 4, 8, 1, 1,13, 1,14, -1,0);
        addg(P.s, 4, 8, 1, 1,15, 1,16, -1,0);
        addg(P.s, 4, 8, 1, 1,17, 1,18, 2,18);    // B18 triple
        addg(P.s, 4, 8, 1, 2,14, 2,15, -1,0);
        addg(P.s, 4, 8, 1, 2,19, -1,0, -1,0);    // pad (bit 0)
        addg(P.s, 4, 8, 1, 2,16, 2,17, 3,17);    // C17 triple
        addg(P.s, 4, 8, 1, 3,15, 3,16, -1,0);
        addg(P.s, 4, 8, 1, 3,18, 3,19, -1,0);    // fused-out (scatter)
    } else if (ph == 2) {
        P.FL = 6; P.GAP = 3;                     // window [0,5] u [9,14]
        addg(P.s, 6, 3, 0, 1,11, 1,12, 2,12);    // fused-in triple (scatter)
        addg(P.s, 6, 3, 1, 1,10, 2,11, -1,0);    // (2,12)<->(1,10) commute: verified
        addg(P.s, 6, 3, 1, 2,13, 3,12, -1,0);
        addg(P.s, 6, 3, 1, 3,13, 3,14, -1,0);    // fused-out (scatter)
    } else {
        P.FL = 12; P.GAP = 8;
        addg(P.s, 12, 8, 0, 1,0, 1,1, -1,0);     // fused-in (contig)
        addg(P.s, 12, 8, 1, 1,2, 1,3, -1,0);
        addg(P.s, 12, 8, 0, 1,4, 1,5, -1,0);
        addg(P.s, 12, 8, 0, 1,6, 1,7, -1,0);
        addg(P.s, 12, 8, 1, 1,8, 1,9, 2,9);      // B9 triple
        addg(P.s, 12, 8, 1, 2,0, 2,1, -1,0);
        addg(P.s, 12, 8, 0, 2,2, 2,3, -1,0);
        addg(P.s, 12, 8, 0, 2,4, 2,5, -1,0);
        addg(P.s, 12, 8, 0, 2,6, 2,7, -1,0);
        addg(P.s, 12, 8, 1, 2,8, 2,10, -1,0);
        addg(P.s, 12, 8, 1, 3,2, 3,3, -1,0);
        addg(P.s, 12, 8, 0, 3,4, 3,5, -1,0);
        addg(P.s, 12, 8, 0, 3,6, 3,7, -1,0);
        addg(P.s, 12, 8, 1, 3,8, 3,9, -1,0);
        addg(P.s, 12, 8, 1, 3,10, 3,11, -1,0);
        addg(P.s, 12, 8, 1, 3,0, 3,1, -1,0);     // fused-out -> IS_FINAL
    }
    return P;
}

// ---- compile-time guards ----
constexpr bool pivots_ok(int ph) {
    PhC P = mk_phase(ph);
    for (int i = 0; i < P.s.ng; ++i)
        if (P.s.g[i].pv[0] == P.s.g[i].pv[1]) return false;
    return true;
}
constexpr bool window_ok(int ph) {
    PhC P = mk_phase(ph);
    for (int i = 0; i < P.s.ng; ++i)
        for (int e = 0; e < 4; ++e) {
            unsigned lm = P.s.g[i].lgxs[e];
            unsigned inv = (lm & ((1u << P.FL) - 1u)) | ((lm >> P.FL) << (P.FL + P.GAP));
            if (inv != P.s.g[i].gxs[e]) return false;
        }
    return true;
}
// third gate must be in-span: m(l2,b2) == m0 ^ m1
constexpr bool triples_ok(int ph) {
    PhC P = mk_phase(ph);
    for (int i = 0; i < P.s.ng; ++i)
        if (P.s.g[i].gt[2].valid) {
            int l = P.s.g[i].gt[2].tix / NQ, b = P.s.g[i].gt[2].tix % NQ;
            if (cpair_mask(l, b) != (P.s.g[i].m01[0] ^ P.s.g[i].m01[1])) return false;
        }
    return true;
}
// Full executed-order circuit equivalence.
constexpr bool order_ok() {
    int el[96] = {}, eb[96] = {}; int n = 0;
    for (int ph = 0; ph < 4; ++ph) {
        PhC P = mk_phase(ph);
        for (int gi = 0; gi < P.s.ng; ++gi)
            for (int j = 0; j < 3; ++j)
                if (P.s.g[gi].gt[j].valid) {
                    el[n] = P.s.g[gi].gt[j].tix / NQ;
                    eb[n] = P.s.g[gi].gt[j].tix % NQ;
                    ++n;
                }
    }
    if (n != 80) return false;
    bool seen[80] = {};
    unsigned M[80] = {}, R[80] = {};
    for (int i = 0; i < n; ++i) {
        int idx = el[i] * NQ + eb[i];
        if (seen[idx]) return false;
        seen[idx] = true;
        M[i] = cpair_mask(el[i], eb[i]);
        R[i] = csel_mask(el[i], eb[i]);
    }
    for (int i = 0; i < n; ++i)
        for (int j = i + 1; j < n; ++j)
            if (el[i] > el[j]) {           // executed earlier, circuit later
                int p1 = __builtin_popcount(M[i] & R[j]) & 1;
                int p2 = __builtin_popcount(M[j] & R[i]) & 1;
                if (p1 != p2) return false;
            }
    return true;
}
static_assert(pivots_ok(0) && pivots_ok(1) && pivots_ok(2) && pivots_ok(3),
              "pivot collision: coset decomposition not bijective");
static_assert(window_ok(0) && window_ok(1) && window_ok(2) && window_ok(3),
              "gate mask outside phase window");
static_assert(triples_ok(0) && triples_ok(1) && triples_ok(2) && triples_ok(3),
              "third gate mask != m0^m1");
static_assert(order_ok(), "executed gate order not circuit-equivalent");

constexpr unsigned max_gxs(const GroupC& g) {
    unsigned m = 0;
    for (int e = 0; e < 4; ++e) if (g.gxs[e] > m) m = g.gxs[e];
    return m;
}

__device__ __forceinline__ unsigned swz(unsigned t) { return t ^ ((t >> 5) & 0xFu); }
__device__ __forceinline__ f32x2 splat2(float x) { f32x2 r = {x, x}; return r; }

template<int FL, int GAP>
__device__ __forceinline__ unsigned gmapF(unsigned t, unsigned mid) {
    if constexpr (FL == 12) return (mid << 12) | t;
    else return (t & ((1u << FL) - 1u)) | ((mid & ((1u << GAP) - 1u)) << FL)
              | ((t >> FL) << (FL + GAP)) | ((mid >> GAP) << (GAP + 12));
}

__device__ __forceinline__ unsigned expand2(unsigned u, int p0, int p1) {
    u = ((u >> p0) << (p0 + 1)) | (u & ((1u << p0) - 1u));
    u = ((u >> p1) << (p1 + 1)) | (u & ((1u << p1) - 1u));
    return u;
}

// Up to 3 butterflies on a 4-amp coset. j=0 pairs (e,e^1), j=1 (e,e^2),
// j=2 (e,e^3) [third gate, mask m0^m1]. G must constant-fold.
#define APPLY_GROUP(G, v, g0, cd, sd)                                           \
    {                                                                            \
        _Pragma("unroll")                                                        \
        for (int j = 0; j < 3; ++j) {                                            \
            if ((G).gt[j].valid) {                                               \
                const f32x2 cc_ = splat2((cd)[j]);                               \
                const unsigned par_ = (unsigned)__popc((g0) & (G).gt[j].R) & 1u; \
                const float sp_ = par_ ? (sd)[j] : -(sd)[j];                     \
                const int xr_ = (j == 0) ? 1 : ((j == 1) ? 2 : 3);               \
                _Pragma("unroll")                                                \
                for (int pr = 0; pr < 2; ++pr) {                                 \
                    const int ea = (j == 0) ? (pr << 1) : pr;                    \
                    const int eb = ea ^ xr_;                                     \
                    const f32x2 sg_ = splat2((((G).gt[j].sb >> ea) & 1u) ? -sp_ : sp_); \
                    const f32x2 a_ = v[ea], b_ = v[eb];                          \
                    v[ea] = cc_ * a_ + sg_ * b_;                                 \
                    v[eb] = cc_ * b_ - sg_ * a_;                                 \
                }                                                                \
            }                                                                    \
        }                                                                        \
    }

// ================= phase kernel =================
// 4096-amp LDS tile; 1024 threads x 4-amp cosets (16 waves/CU); group 0
// fused into stage-in, last group into stage-out.
template<int PH, bool IS_INIT, bool IS_FINAL>
__global__ __launch_bounds__(1024) void k_phase(f32x2* __restrict__ st,
                                                const float* __restrict__ qr,
                                                const float* __restrict__ qi,
                                                const float* __restrict__ theta,
                                                float* __restrict__ out) {
    constexpr PhC P = mk_phase(PH);
    constexpr int FL = P.FL, GAP = P.GAP, NG = P.s.ng;
    __shared__ __align__(16) f32x2 lds[4096];
    __shared__ float2 trigS[80];
    const unsigned tid = threadIdx.x;
    const unsigned mid = blockIdx.x;

    if (tid < 80) {
        int l = tid / NQ, b = tid % NQ;
        float th = 0.5f * theta[l * NQ + (NQ - 1 - b)];
        trigS[tid] = make_float2(cosf(th), sinf(th));
    }

    // ---- stage-in, fused group 0 ----
    {
        constexpr GroupC G = P.s.g[0];
        constexpr bool CIN = (max_gxs(G) < 4u);   // coset = 4 contiguous amps
        const unsigned t0 = expand2(tid, G.pv[0], G.pv[1]);
        const unsigned g0 = gmapF<FL, GAP>(t0, mid);
        f32x2 v[4];
        if constexpr (IS_INIT) {
            const f32x4* r4 = reinterpret_cast<const f32x4*>(qr);
            const f32x4* i4 = reinterpret_cast<const f32x4*>(qi);
            f32x4 ra = r4[g0 >> 2], ia = i4[g0 >> 2];
            const float re[4] = {ra.x, ra.y, ra.z, ra.w};
            const float im[4] = {ia.x, ia.y, ia.z, ia.w};
#pragma unroll
            for (int e = 0; e < 4; ++e) v[e] = f32x2{re[G.gxs[e] & 3u], im[G.gxs[e] & 3u]};
        } else if constexpr (CIN) {
            const f32x4* s4 = reinterpret_cast<const f32x4*>(st);
            f32x4 q[2];
            q[0] = s4[g0 >> 1]; q[1] = s4[(g0 >> 1) + 1];
            const float* qq = reinterpret_cast<const float*>(q);
#pragma unroll
            for (int e = 0; e < 4; ++e) {
                const unsigned j = G.gxs[e] & 3u;
                v[e] = f32x2{qq[2 * j], qq[2 * j + 1]};
            }
        } else {
#pragma unroll
            for (int e = 0; e < 4; ++e) v[e] = st[g0 ^ G.gxs[e]];
        }
        float cd[3], sd[3];
#pragma unroll
        for (int j = 0; j < 3; ++j)
            if (G.gt[j].valid) {
                float th = 0.5f * theta[G.gt[j].thix];
                cd[j] = cosf(th); sd[j] = sinf(th);
            }
        APPLY_GROUP(G, v, g0, cd, sd);
#pragma unroll
        for (int e = 0; e < 4; ++e) lds[swz(t0 ^ G.lgxs[e])] = v[e];
        // first in-LDS round has bar=1 -> provides the trigS/stage sync.
    }

    // ---- in-LDS rounds: groups 1 .. NG-2 ----
#pragma unroll
    for (int gi = 1; gi < NG - 1; ++gi) {
        if (P.s.bar[gi]) __syncthreads();
        else __builtin_amdgcn_wave_barrier();
        const unsigned t0 = expand2(tid, P.s.g[gi].pv[0], P.s.g[gi].pv[1]);
        const unsigned g0 = gmapF<FL, GAP>(t0, mid);
        const unsigned sz0 = swz(t0);
        f32x2 v[4]; unsigned ad[4];
#pragma unroll
        for (int e = 0; e < 4; ++e) {
            ad[e] = sz0 ^ cswz(P.s.g[gi].lgxs[e]);    // folds to immediate XOR
            v[e] = lds[ad[e]];
        }
        float cd[3], sd[3];
#pragma unroll
        for (int j = 0; j < 3; ++j)
            if (P.s.g[gi].gt[j].valid) {
                float2 cs = trigS[P.s.g[gi].gt[j].tix];
                cd[j] = cs.x; sd[j] = cs.y;
            }
        APPLY_GROUP(P.s.g[gi], v, g0, cd, sd);
#pragma unroll
        for (int e = 0; e < 4; ++e) lds[ad[e]] = v[e];
    }

    __syncthreads();

    // ---- stage-out, fused group NG-1 ----
    {
        constexpr GroupC G = P.s.g[NG - 1];
        const unsigned t0 = expand2(tid, G.pv[0], G.pv[1]);
        const unsigned g0 = gmapF<FL, GAP>(t0, mid);
        f32x2 v[4];
#pragma unroll
        for (int e = 0; e < 4; ++e) v[e] = lds[swz(t0 ^ G.lgxs[e])];
        float cd[3], sd[3];
#pragma unroll
        for (int j = 0; j < 3; ++j)
            if (G.gt[j].valid) {
                float2 cs = trigS[G.gt[j].tix];
                cd[j] = cs.x; sd[j] = cs.y;
            }
        APPLY_GROUP(G, v, g0, cd, sd);
        if constexpr (IS_FINAL) {
            // out[ginv4(g0 ^ gxs[e])]: coset spans bits {0,1}; ginv4 is
            // identity on bits [0,1] -> outputs fill the 4-aligned block of
            // i0 = ginv4(g0). base = i0&~3, slot = (i0&3) ^ (gxs[e]&3).
            const unsigned i0 = g0 ^ (g0 >> 4) ^ (g0 >> 8) ^ (g0 >> 12) ^ (g0 >> 16);
            const unsigned base = i0 & ~3u;
            const unsigned lo = i0 & 3u;
            f32x2 u[4];
#pragma unroll
            for (int e = 0; e < 4; ++e) u[G.gxs[e] & 3u] = v[e];   // static perm
#pragma unroll
            for (int bit = 1; bit <= 2; bit <<= 1) {               // XOR-perm by lo
                const bool c = (lo & (unsigned)bit) != 0u;
                f32x2 t[4];
#pragma unroll
                for (int k = 0; k < 4; ++k) t[k] = c ? u[k ^ bit] : u[k];
#pragma unroll
                for (int k = 0; k < 4; ++k) u[k] = t[k];
            }
            float4* oR = reinterpret_cast<float4*>(out + base);
            float4* oI = reinterpret_cast<float4*>(out + DIM + base);
            oR[0] = make_float4(u[0].x, u[1].x, u[2].x, u[3].x);
            oI[0] = make_float4(u[0].y, u[1].y, u[2].y, u[3].y);
        } else {
#pragma unroll
            for (int e = 0; e < 4; ++e) st[g0 ^ G.gxs[e]] = v[e];
        }
    }
}

// ================= launch =================
extern "C" void kernel_launch(void* const* d_in, const int* in_sizes, int n_in,
                              void* d_out, int out_size, void* d_ws, size_t ws_size,
                              hipStream_t stream) {
    const float* theta = (const float*)d_in[0];   // (4,20) float32
    const float* qr    = (const float*)d_in[1];
    const float* qi    = (const float*)d_in[2];
    float* out = (float*)d_out;
    f32x2* st = (f32x2*)d_ws;                     // 8 MiB interleaved state

    k_phase<0, true,  false><<<256, 1024, 0, stream>>>(st, qr, qi, theta, out);
    k_phase<1, false, false><<<256, 1024, 0, stream>>>(st, qr, qi, theta, out);
    k_phase<2, false, false><<<256, 1024, 0, stream>>>(st, qr, qi, theta, out);
    k_phase<3, false, true ><<<256, 1024, 0, stream>>>(st, qr, qi, theta, out);
}